// Round 8
// baseline (169548.352 us; speedup 1.0000x reference)
//
#include <hip/hip_runtime.h>
#include <math.h>

// Problem constants
#define HH    1028        // real hidden size
#define TT    16384       // timesteps
#define UP    1056        // padded hidden (= 16*66 = 8*132)
#define HSU   1056        // (val,tag) u64 pairs per ring row
#define HS    1056        // floats per h2 history row
#define NWG0  66          // layer-0 WGs, 16 units each (1 unit per wave)
#define NWG1  132         // layer-1 WGs, 8 units each (2 waves per unit)
#define NWGT  (NWG0 + NWG1)
#define R0    1024        // h1 ring depth
#define R0M   (R0 - 1)
#define R1M   15          // h2 ring depth 16

typedef unsigned long long u64;

// ---------- MALL-coherent primitives ----------
__device__ __forceinline__ u64 ld_u64(const u64* p) {
    return __hip_atomic_load(p, __ATOMIC_RELAXED, __HIP_MEMORY_SCOPE_AGENT);
}
__device__ __forceinline__ void st_u64(u64* p, u64 v) {
    __hip_atomic_store(p, v, __ATOMIC_RELAXED, __HIP_MEMORY_SCOPE_AGENT);
}
__device__ __forceinline__ unsigned ld_u32(const unsigned* p) {
    return __hip_atomic_load(p, __ATOMIC_RELAXED, __HIP_MEMORY_SCOPE_AGENT);
}
__device__ __forceinline__ void st_u32(unsigned* p, unsigned v) {
    __hip_atomic_store(p, v, __ATOMIC_RELAXED, __HIP_MEMORY_SCOPE_AGENT);
}
__device__ __forceinline__ float sigmf(float x) { return 1.0f / (1.0f + expf(-x)); }
__device__ __forceinline__ u64 pack(unsigned tag, float v) {
    return ((u64)tag << 32) | (u64)__float_as_uint(v);
}

// Stage 66 (val,tag) pairs [base, base+66) into LDS; exec-masked retries.
__device__ __forceinline__ void stage66(const u64* __restrict__ src, float* __restrict__ lds,
                                        int base, int lane, unsigned want, long long& budget) {
    const int i0 = base + lane, i1 = base + 64 + lane;
    bool d0 = false, d1 = (lane >= 2);
    for (;;) {
        if (!d0) { u64 v = ld_u64(src + i0);
                   if ((unsigned)(v >> 32) == want) { lds[i0] = __uint_as_float((unsigned)v); d0 = true; } }
        if (!d1) { u64 v = ld_u64(src + i1);
                   if ((unsigned)(v >> 32) == want) { lds[i1] = __uint_as_float((unsigned)v); d1 = true; } }
        if (__all(d0 & d1)) break;
        if (--budget < 0) break;          // hang safety valve
        __builtin_amdgcn_s_sleep(1);
    }
}

// Stage 132 pairs [base, base+132).
__device__ __forceinline__ void stage132(const u64* __restrict__ src, float* __restrict__ lds,
                                         int base, int lane, unsigned want, long long& budget) {
    const int i0 = base + lane, i1 = base + 64 + lane, i2 = base + 128 + lane;
    bool d0 = false, d1 = false, d2 = (lane >= 4);
    for (;;) {
        if (!d0) { u64 v = ld_u64(src + i0);
                   if ((unsigned)(v >> 32) == want) { lds[i0] = __uint_as_float((unsigned)v); d0 = true; } }
        if (!d1) { u64 v = ld_u64(src + i1);
                   if ((unsigned)(v >> 32) == want) { lds[i1] = __uint_as_float((unsigned)v); d1 = true; } }
        if (!d2) { u64 v = ld_u64(src + i2);
                   if ((unsigned)(v >> 32) == want) { lds[i2] = __uint_as_float((unsigned)v); d2 = true; } }
        if (__all(d0 & d1 & d2)) break;
        if (--budget < 0) break;
        __builtin_amdgcn_s_sleep(1);
    }
}

// ---------- fused 2-layer LSTM recurrence ----------
__global__ __launch_bounds__(1024, 4) void wn_fused(
    const float* __restrict__ x,
    const float* __restrict__ w_ih0, const float* __restrict__ w_hh0,
    const float* __restrict__ b_ih0, const float* __restrict__ b_hh0,
    const float* __restrict__ w_ih1, const float* __restrict__ w_hh1,
    const float* __restrict__ b_ih1, const float* __restrict__ b_hh1,
    u64* __restrict__ ring0,                  // [R0][HSU] (val,tag) of h1
    u64* __restrict__ ring1,                  // [16][HSU] (val,tag) of h2
    float* __restrict__ h2hist,               // [TT][HS] plain h2 for projection
    unsigned* __restrict__ l1prog)            // L1 WG0 progress (poison-tolerant)
{
    __shared__ float smem[4 * UP + 64];       // L0: h[2][UP]; L1: a[2][UP] b[2][UP] part[64]
    const int tid  = threadIdx.x;
    const int lane = tid & 63;
    const int w    = tid >> 6;                // wave 0..15
    const int g    = lane >> 4;               // gate 0..3 (i,f,g,o)
    const int k0   = lane & 15;               // K-slice: cols [k0*66, k0*66+66)

    if (blockIdx.x < NWG0) {
        // ========== layer 0 : 16 units, wave w owns unit wg*16+w entirely ==========
        const int wg = blockIdx.x;
        const int u  = wg * 16 + w;
        const bool real = (u < HH);
        const int row = g * HH + (real ? u : 0);

        float wv[16][4], wt0 = 0.f, wt1 = 0.f;
#pragma unroll
        for (int m = 0; m < 16; ++m) {
            const int j = k0 * 66 + m * 4;
#pragma unroll
            for (int q = 0; q < 4; ++q)
                wv[m][q] = (real && j + q < HH) ? w_hh0[(size_t)row * HH + j + q] : 0.0f;
        }
        {   const int j = k0 * 66 + 64;
            wt0 = (real && j     < HH) ? w_hh0[(size_t)row * HH + j]     : 0.0f;
            wt1 = (real && j + 1 < HH) ? w_hh0[(size_t)row * HH + j + 1] : 0.0f; }
#pragma unroll
        for (int m = 0; m < 16; ++m)
#pragma unroll
            for (int q = 0; q < 4; ++q) asm volatile("" : "+v"(wv[m][q]));
        asm volatile("" : "+v"(wt0), "+v"(wt1));

        const float wx = real ? w_ih0[row] : 0.0f;
        const float bs = real ? (b_ih0[row] + b_hh0[row]) : 0.0f;
        for (int i = tid; i < 2 * UP; i += 1024) smem[i] = 0.0f;
        __syncthreads();

        long long budget = 20000000LL;
        float c_reg = 0.0f;
        for (int t = 0; t < TT; ++t) {
            const float xt = x[t];
            float* hb = smem + (t & 1) * UP;
            if (t > 0)                         // every wave stages its 66-pair slice
                stage66(ring0 + (size_t)((t - 1) & R0M) * HSU, hb, w * 66, lane,
                        (unsigned)t, budget);
            __syncthreads();                   // the ONLY barrier per step
            float acc = 0.0f;
#pragma unroll
            for (int m = 0; m < 16; ++m) {
                const float4 hv = *(const float4*)&hb[k0 * 66 + m * 4];
                acc = fmaf(wv[m][0], hv.x, acc);
                acc = fmaf(wv[m][1], hv.y, acc);
                acc = fmaf(wv[m][2], hv.z, acc);
                acc = fmaf(wv[m][3], hv.w, acc);
            }
            {   const float2 hv = *(const float2*)&hb[k0 * 66 + 64];
                acc = fmaf(wt0, hv.x, acc);
                acc = fmaf(wt1, hv.y, acc); }
#pragma unroll
            for (int off = 1; off < 16; off <<= 1) acc += __shfl_xor(acc, off);
            if (k0 == 0) acc += fmaf(xt, wx, bs);   // input+bias added ONCE, post-reduce
            const float gi = __shfl(acc, 0);
            const float gf = __shfl(acc, 16);
            const float gg = __shfl(acc, 32);
            const float go = __shfl(acc, 48);
            const float iv = sigmf(gi), fv = sigmf(gf), gv = tanhf(gg), ov = sigmf(go);
            c_reg = fv * c_reg + iv * gv;
            float hv = ov * tanhf(c_reg);
            if (!real) hv = 0.0f;
            // ring backpressure: never lap L1 (wave 0 only; others catch at barrier)
            if (w == 0 && lane == 0 && t > 0 && (t & 255) == 0) {
                for (;;) {
                    unsigned p = ld_u32(l1prog);
                    if ((int)t - (int)p < R0 - 256) break;
                    if (--budget < 0) break;
                    __builtin_amdgcn_s_sleep(32);
                }
            }
            if (lane == 0)                     // per-wave publish, fire-and-forget
                st_u64(ring0 + (size_t)(t & R0M) * HSU + u, pack((unsigned)(t + 1), hv));
        }
    } else {
        // ========== layer 1 : 8 units; waves w/w+8 split ih/hh of unit wg*8+w ==========
        float* aB   = smem;                    // h1[t]   [2][UP]
        float* bB   = smem + 2 * UP;           // h2[t-1] [2][UP]
        float* part = smem + 4 * UP;           // [16][4] partials
        const int wg = blockIdx.x - NWG0;      // 0..131
        const bool ihHalf = (w < 8);
        const int du = ihHalf ? w : (w - 8);
        const int u  = wg * 8 + du;
        const bool real = (u < HH);
        const int row = g * HH + (real ? u : 0);
        const float* __restrict__ W = ihHalf ? w_ih1 : w_hh1;

        float wv[16][4], wt0 = 0.f, wt1 = 0.f;
#pragma unroll
        for (int m = 0; m < 16; ++m) {
            const int j = k0 * 66 + m * 4;
#pragma unroll
            for (int q = 0; q < 4; ++q)
                wv[m][q] = (real && j + q < HH) ? W[(size_t)row * HH + j + q] : 0.0f;
        }
        {   const int j = k0 * 66 + 64;
            wt0 = (real && j     < HH) ? W[(size_t)row * HH + j]     : 0.0f;
            wt1 = (real && j + 1 < HH) ? W[(size_t)row * HH + j + 1] : 0.0f; }
#pragma unroll
        for (int m = 0; m < 16; ++m)
#pragma unroll
            for (int q = 0; q < 4; ++q) asm volatile("" : "+v"(wv[m][q]));
        asm volatile("" : "+v"(wt0), "+v"(wt1));

        const float bs = real ? (b_ih1[row] + b_hh1[row]) : 0.0f;
        for (int i = tid; i < 4 * UP + 64; i += 1024) smem[i] = 0.0f;
        __syncthreads();

        long long budget = 20000000LL;
        float c_reg = 0.0f;
        for (int t = 0; t < TT; ++t) {
            float* ab = aB + (t & 1) * UP;
            float* bb = bB + (t & 1) * UP;
            if (ihHalf)                        // waves 0-7: stage h1[t] (tag t+1)
                stage132(ring0 + (size_t)(t & R0M) * HSU, ab, du * 132, lane,
                         (unsigned)(t + 1), budget);
            else if (t > 0)                    // waves 8-15: stage h2[t-1] (tag t)
                stage132(ring1 + (size_t)((t - 1) & R1M) * HSU, bb, du * 132, lane,
                         (unsigned)t, budget);
            __syncthreads();                   // barrier A: stage visible
            const float* hb = ihHalf ? ab : bb;
            float acc = 0.0f;
#pragma unroll
            for (int m = 0; m < 16; ++m) {
                const float4 hv = *(const float4*)&hb[k0 * 66 + m * 4];
                acc = fmaf(wv[m][0], hv.x, acc);
                acc = fmaf(wv[m][1], hv.y, acc);
                acc = fmaf(wv[m][2], hv.z, acc);
                acc = fmaf(wv[m][3], hv.w, acc);
            }
            {   const float2 hv = *(const float2*)&hb[k0 * 66 + 64];
                acc = fmaf(wt0, hv.x, acc);
                acc = fmaf(wt1, hv.y, acc); }
#pragma unroll
            for (int off = 1; off < 16; off <<= 1) acc += __shfl_xor(acc, off);
            if (k0 == 0) part[w * 4 + g] = acc;
            __syncthreads();                   // barrier B: partials visible
            if (ihHalf) {                      // finalize + publish (waves 8-15 run ahead)
                float tot = part[w * 4 + g] + part[(w + 8) * 4 + g] + bs;
                const float gi = __shfl(tot, 0);
                const float gf = __shfl(tot, 16);
                const float gg = __shfl(tot, 32);
                const float go = __shfl(tot, 48);
                const float iv = sigmf(gi), fv = sigmf(gf), gv = tanhf(gg), ov = sigmf(go);
                c_reg = fv * c_reg + iv * gv;
                float hv = ov * tanhf(c_reg);
                if (!real) hv = 0.0f;
                if (lane == 0) {
                    st_u64(ring1 + (size_t)(t & R1M) * HSU + u, pack((unsigned)(t + 1), hv));
                    h2hist[(size_t)t * HS + u] = hv;   // normal store, kernel-end flush
                }
            }
            if (w == 15 && lane == 0 && wg == 0 && (t & 255) == 255)
                st_u32(l1prog, (unsigned)(t + 1));     // backpressure progress
        }
    }
}

// ---------- final projection: out[t] = lin_w . h2[t] + lin_b ----------
__global__ __launch_bounds__(256) void wn_proj(
    const float* __restrict__ h2,
    const float* __restrict__ lin_w,
    const float* __restrict__ lin_b,
    float* __restrict__ out)
{
    const int lane = threadIdx.x & 63;
    const int wv   = threadIdx.x >> 6;
    const int t    = blockIdx.x * 4 + wv;
    const float* hp = h2 + (size_t)t * HS;
    float acc = 0.0f;
#pragma unroll
    for (int m = 0; m < 4; ++m) {
        const int j = lane * 4 + m * 256;        // covers [0,1024)
        const float4 h4 = *(const float4*)(hp + j);
        const float4 w4 = *(const float4*)(lin_w + j);
        acc += h4.x * w4.x + h4.y * w4.y + h4.z * w4.z + h4.w * w4.w;
    }
    if (lane == 0) {
#pragma unroll
        for (int j = 1024; j < HH; ++j) acc += hp[j] * lin_w[j];
    }
#pragma unroll
    for (int off = 1; off < 64; off <<= 1) acc += __shfl_xor(acc, off);
    if (lane == 0) out[t] = acc + lin_b[0];
}

extern "C" void kernel_launch(void* const* d_in, const int* in_sizes, int n_in,
                              void* d_out, int out_size, void* d_ws, size_t ws_size,
                              hipStream_t stream) {
    const float* x     = (const float*)d_in[0];
    const float* w_ih0 = (const float*)d_in[1];
    const float* w_hh0 = (const float*)d_in[2];
    const float* b_ih0 = (const float*)d_in[3];
    const float* b_hh0 = (const float*)d_in[4];
    const float* w_ih1 = (const float*)d_in[5];
    const float* w_hh1 = (const float*)d_in[6];
    const float* b_ih1 = (const float*)d_in[7];
    const float* b_hh1 = (const float*)d_in[8];
    const float* lin_w = (const float*)d_in[9];
    const float* lin_b = (const float*)d_in[10];
    float* out = (float*)d_out;

    char* ws = (char*)d_ws;
    const size_t R0B = (size_t)R0 * HSU * 8;        //  8,650,752
    const size_t R1B = (size_t)16 * HSU * 8;        //    135,168
    const size_t H2B = (size_t)TT * HS * 4;         // 69,206,016
    u64* ring0 = (u64*)(ws);
    u64* ring1 = (u64*)(ws + R0B);
    float* h2hist = (float*)(ws + R0B + R1B);
    unsigned* l1prog = (unsigned*)(ws + R0B + R1B + H2B);
    // No init kernel: 0xAA poison never matches any tag (1..16384), and the
    // poisoned l1prog reads as negative -> L0 throttles until L1 publishes.

    wn_fused<<<NWGT, 1024, 0, stream>>>(x, w_ih0, w_hh0, b_ih0, b_hh0,
                                        w_ih1, w_hh1, b_ih1, b_hh1,
                                        ring0, ring1, h2hist, l1prog);
    wn_proj<<<TT / 4, 256, 0, stream>>>(h2hist, lin_w, lin_b, out);
}

// Round 9
// 43453.088 us; speedup vs baseline: 3.9019x; 3.9019x over previous
//
#include <hip/hip_runtime.h>
#include <math.h>

// Problem constants
#define HH    1028        // real hidden size
#define TT    16384       // timesteps
#define UP    1056        // padded hidden (= 16*66 = 8*132)
#define HSU   1056        // (val,tag) u64 pairs per ring row
#define HS    1056        // floats per h2 history row
#define NWG0  66          // layer-0 WGs, 16 units each
#define NWG1  132         // layer-1 WGs, 8 units each
#define NWGT  (NWG0 + NWG1)
#define R0    1024        // h1 ring depth
#define R0M   (R0 - 1)
#define R1M   15          // h2 ring depth 16

typedef unsigned long long u64;

// ---------- MALL-coherent primitives ----------
__device__ __forceinline__ u64 ld_u64(const u64* p) {
    return __hip_atomic_load(p, __ATOMIC_RELAXED, __HIP_MEMORY_SCOPE_AGENT);
}
__device__ __forceinline__ void st_u64(u64* p, u64 v) {
    __hip_atomic_store(p, v, __ATOMIC_RELAXED, __HIP_MEMORY_SCOPE_AGENT);
}
__device__ __forceinline__ unsigned ld_u32(const unsigned* p) {
    return __hip_atomic_load(p, __ATOMIC_RELAXED, __HIP_MEMORY_SCOPE_AGENT);
}
__device__ __forceinline__ void st_u32(unsigned* p, unsigned v) {
    __hip_atomic_store(p, v, __ATOMIC_RELAXED, __HIP_MEMORY_SCOPE_AGENT);
}
__device__ __forceinline__ float sigmf(float x) { return 1.0f / (1.0f + expf(-x)); }
__device__ __forceinline__ u64 pack(unsigned tag, float v) {
    return ((u64)tag << 32) | (u64)__float_as_uint(v);
}

// Stage 132 (val,tag) pairs [base, base+132) into LDS; exec-masked retries.
__device__ __forceinline__ void stage132(const u64* __restrict__ src, float* __restrict__ lds,
                                         int base, int lane, unsigned want, long long& budget) {
    const int i0 = base + lane, i1 = base + 64 + lane, i2 = base + 128 + lane;
    bool d0 = false, d1 = false, d2 = (lane >= 4);
    for (;;) {
        if (!d0) { u64 v = ld_u64(src + i0);
                   if ((unsigned)(v >> 32) == want) { lds[i0] = __uint_as_float((unsigned)v); d0 = true; } }
        if (!d1) { u64 v = ld_u64(src + i1);
                   if ((unsigned)(v >> 32) == want) { lds[i1] = __uint_as_float((unsigned)v); d1 = true; } }
        if (!d2) { u64 v = ld_u64(src + i2);
                   if ((unsigned)(v >> 32) == want) { lds[i2] = __uint_as_float((unsigned)v); d2 = true; } }
        if (__all(d0 & d1 & d2)) break;
        if (--budget < 0) break;          // hang safety valve
        __builtin_amdgcn_s_sleep(1);
    }
}

// Stage 264 pairs [base, base+264).
__device__ __forceinline__ void stage264(const u64* __restrict__ src, float* __restrict__ lds,
                                         int base, int lane, unsigned want, long long& budget) {
    const int i0 = base + lane, i1 = i0 + 64, i2 = i0 + 128, i3 = i0 + 192, i4 = i0 + 256;
    bool d0 = false, d1 = false, d2 = false, d3 = false, d4 = (lane >= 8);
    for (;;) {
        if (!d0) { u64 v = ld_u64(src + i0);
                   if ((unsigned)(v >> 32) == want) { lds[i0] = __uint_as_float((unsigned)v); d0 = true; } }
        if (!d1) { u64 v = ld_u64(src + i1);
                   if ((unsigned)(v >> 32) == want) { lds[i1] = __uint_as_float((unsigned)v); d1 = true; } }
        if (!d2) { u64 v = ld_u64(src + i2);
                   if ((unsigned)(v >> 32) == want) { lds[i2] = __uint_as_float((unsigned)v); d2 = true; } }
        if (!d3) { u64 v = ld_u64(src + i3);
                   if ((unsigned)(v >> 32) == want) { lds[i3] = __uint_as_float((unsigned)v); d3 = true; } }
        if (!d4) { u64 v = ld_u64(src + i4);
                   if ((unsigned)(v >> 32) == want) { lds[i4] = __uint_as_float((unsigned)v); d4 = true; } }
        if (__all(d0 & d1 & d2 & d3 & d4)) break;
        if (--budget < 0) break;
        __builtin_amdgcn_s_sleep(1);
    }
}

// ---------- fused 2-layer LSTM recurrence ----------
__global__ __launch_bounds__(1024, 4) void wn_fused(
    const float* __restrict__ x,
    const float* __restrict__ w_ih0, const float* __restrict__ w_hh0,
    const float* __restrict__ b_ih0, const float* __restrict__ b_hh0,
    const float* __restrict__ w_ih1, const float* __restrict__ w_hh1,
    const float* __restrict__ b_ih1, const float* __restrict__ b_hh1,
    u64* __restrict__ ring0,                  // [R0][HSU] (val,tag) of h1
    u64* __restrict__ ring1,                  // [16][HSU] (val,tag) of h2
    float* __restrict__ h2hist,               // [TT][HS] plain h2 for projection
    unsigned* __restrict__ l1prog)            // L1 WG0 progress (poison-tolerant)
{
    __shared__ float smem[4 * UP + 128];
    const int tid  = threadIdx.x;
    const int lane = tid & 63;
    const int w    = tid >> 6;                // wave 0..15

    for (int i = tid; i < 4 * UP + 128; i += 1024) smem[i] = 0.0f;

    if (blockIdx.x < NWG0) {
        // ========== layer 0 : 16 units/WG, rows = 4 gates x 16 units, 16 lanes/row ==========
        float* hbuf = smem;                   // [2][UP] staged h1
        float* gbuf = smem + 2 * UP;          // [2][64] gate pre-activations
        const int wg   = blockIdx.x;
        const int row  = tid >> 4;            // 0..63 = gate*16 + du
        const int k0   = tid & 15;
        const int gate = row >> 4;
        const int du   = row & 15;
        const int u    = wg * 16 + du;
        const bool real = (u < HH);
        const int wr   = gate * HH + (real ? u : 0);

        float wv[16][4], wt0 = 0.f, wt1 = 0.f;
#pragma unroll
        for (int m = 0; m < 16; ++m) {
            const int j = k0 * 4 + m * 64;
#pragma unroll
            for (int q = 0; q < 4; ++q)
                wv[m][q] = (real && j + q < HH) ? w_hh0[(size_t)wr * HH + j + q] : 0.0f;
        }
        {   const int j = 1024 + k0 * 2;
            wt0 = (real && j     < HH) ? w_hh0[(size_t)wr * HH + j]     : 0.0f;
            wt1 = (real && j + 1 < HH) ? w_hh0[(size_t)wr * HH + j + 1] : 0.0f; }
#pragma unroll
        for (int m = 0; m < 16; ++m)
#pragma unroll
            for (int q = 0; q < 4; ++q) asm volatile("" : "+v"(wv[m][q]));
        asm volatile("" : "+v"(wt0), "+v"(wt1));

        const float wx = real ? w_ih0[wr] : 0.0f;
        const float bs = real ? (b_ih0[wr] + b_hh0[wr]) : 0.0f;
        __syncthreads();

        long long budget = 20000000LL;
        float c_reg = 0.0f;
        for (int t = 0; t < TT; ++t) {
            // ---- phase P: epilogue+publish(t-1) [wave0] || poll+stage h1(t-1) [waves4-11] ----
            if (t > 0) {
                if (w == 0) {
                    const float* gl = gbuf + ((t - 1) & 1) * 64;
                    if (lane < 16) {
                        const float gi = gl[lane], gf = gl[16 + lane];
                        const float gg = gl[32 + lane], go = gl[48 + lane];
                        const float iv = sigmf(gi), fv = sigmf(gf), gv = tanhf(gg), ov = sigmf(go);
                        c_reg = fv * c_reg + iv * gv;
                        float hv = ov * tanhf(c_reg);
                        if (wg * 16 + lane >= HH) hv = 0.0f;
                        st_u64(ring0 + (size_t)((t - 1) & R0M) * HSU + wg * 16 + lane,
                               pack((unsigned)t, hv));      // coalesced 128B burst
                    }
                } else if (w >= 4 && w < 12) {
                    stage132(ring0 + (size_t)((t - 1) & R0M) * HSU, hbuf + (t & 1) * UP,
                             (w - 4) * 132, lane, (unsigned)t, budget);
                } else if (w == 1 && lane == 0 && (t & 255) == 0) {
                    for (;;) {                 // ring backpressure: never lap L1
                        unsigned p = ld_u32(l1prog);
                        if ((int)t - (int)p < R0 - 256) break;
                        if (--budget < 0) break;
                        __builtin_amdgcn_s_sleep(32);
                    }
                }
            }
            __syncthreads();                   // A: stage visible
            const float* hb = hbuf + (t & 1) * UP;
            float acc = 0.0f;
#pragma unroll
            for (int m = 0; m < 16; ++m) {
                const float4 hv = *(const float4*)&hb[k0 * 4 + m * 64];
                acc = fmaf(wv[m][0], hv.x, acc);
                acc = fmaf(wv[m][1], hv.y, acc);
                acc = fmaf(wv[m][2], hv.z, acc);
                acc = fmaf(wv[m][3], hv.w, acc);
            }
            {   const float2 hv = *(const float2*)&hb[1024 + k0 * 2];
                acc = fmaf(wt0, hv.x, acc);
                acc = fmaf(wt1, hv.y, acc); }
#pragma unroll
            for (int off = 1; off < 16; off <<= 1) acc += __shfl_xor(acc, off);
            if (k0 == 0) gbuf[(t & 1) * 64 + row] = acc + x[t] * wx + bs;
            __syncthreads();                   // B: gates visible for next P
        }
        // final epilogue+publish for t = TT-1
        if (w == 0 && lane < 16) {
            const float* gl = gbuf + ((TT - 1) & 1) * 64;
            const float gi = gl[lane], gf = gl[16 + lane];
            const float gg = gl[32 + lane], go = gl[48 + lane];
            const float iv = sigmf(gi), fv = sigmf(gf), gv = tanhf(gg), ov = sigmf(go);
            c_reg = fv * c_reg + iv * gv;
            float hv = ov * tanhf(c_reg);
            if (wg * 16 + lane >= HH) hv = 0.0f;
            st_u64(ring0 + (size_t)((TT - 1) & R0M) * HSU + wg * 16 + lane,
                   pack((unsigned)TT, hv));
        }
    } else {
        // ========== layer 1 : 8 units/WG, rows = 4 gates x 8 units, 32 lanes/row ==========
        float* abuf = smem;                   // [2][UP] h1[t]
        float* bbuf = smem + 2 * UP;          // [2][UP] h2[t-1]
        float* gbuf = smem + 4 * UP;          // [2][32]
        const int wg   = blockIdx.x - NWG0;   // 0..131
        const int row  = tid >> 5;            // 0..31 = gate*8 + du
        const int k0   = tid & 31;
        const int gate = row >> 3;
        const int du   = row & 7;
        const int u    = wg * 8 + du;
        const bool real = (u < HH);
        const int wr   = gate * HH + (real ? u : 0);

        float wiv[8][4], whv[8][4], wit = 0.f, wht = 0.f;
#pragma unroll
        for (int m = 0; m < 8; ++m) {
            const int j = k0 * 4 + m * 128;
#pragma unroll
            for (int q = 0; q < 4; ++q) {
                const bool inb = real && (j + q < HH);
                wiv[m][q] = inb ? w_ih1[(size_t)wr * HH + j + q] : 0.0f;
                whv[m][q] = inb ? w_hh1[(size_t)wr * HH + j + q] : 0.0f;
            }
        }
        {   const int j = 1024 + k0;
            wit = (real && j < HH) ? w_ih1[(size_t)wr * HH + j] : 0.0f;
            wht = (real && j < HH) ? w_hh1[(size_t)wr * HH + j] : 0.0f; }
#pragma unroll
        for (int m = 0; m < 8; ++m)
#pragma unroll
            for (int q = 0; q < 4; ++q) {
                asm volatile("" : "+v"(wiv[m][q]));
                asm volatile("" : "+v"(whv[m][q]));
            }
        asm volatile("" : "+v"(wit), "+v"(wht));
        const float bs = real ? (b_ih1[wr] + b_hh1[wr]) : 0.0f;
        __syncthreads();

        long long budget = 20000000LL;
        float c_reg = 0.0f;
        for (int t = 0; t < TT; ++t) {
            // ---- phase P: epilogue(t-1) [wave0] || stage h2(t-1) [w4-11] || stage h1(t) [w12-15] ----
            if (w == 0) {
                if (t > 0) {
                    const float* gl = gbuf + ((t - 1) & 1) * 32;
                    if (lane < 8) {
                        const float gi = gl[lane], gf = gl[8 + lane];
                        const float gg = gl[16 + lane], go = gl[24 + lane];
                        const float iv = sigmf(gi), fv = sigmf(gf), gv = tanhf(gg), ov = sigmf(go);
                        c_reg = fv * c_reg + iv * gv;
                        float hv = ov * tanhf(c_reg);
                        if (wg * 8 + lane >= HH) hv = 0.0f;
                        st_u64(ring1 + (size_t)((t - 1) & R1M) * HSU + wg * 8 + lane,
                               pack((unsigned)t, hv));     // coalesced 64B burst
                        h2hist[(size_t)(t - 1) * HS + wg * 8 + lane] = hv;
                    }
                }
            } else if (w >= 4 && w < 12) {
                if (t > 0)
                    stage132(ring1 + (size_t)((t - 1) & R1M) * HSU, bbuf + (t & 1) * UP,
                             (w - 4) * 132, lane, (unsigned)t, budget);
            } else if (w >= 12) {
                stage264(ring0 + (size_t)(t & R0M) * HSU, abuf + (t & 1) * UP,
                         (w - 12) * 264, lane, (unsigned)(t + 1), budget);
            }
            __syncthreads();                   // A
            const float* ab = abuf + (t & 1) * UP;
            const float* bb = bbuf + (t & 1) * UP;
            float acc = 0.0f;
#pragma unroll
            for (int m = 0; m < 8; ++m) {
                const float4 ha = *(const float4*)&ab[k0 * 4 + m * 128];
                const float4 hb2 = *(const float4*)&bb[k0 * 4 + m * 128];
                acc = fmaf(wiv[m][0], ha.x, acc);
                acc = fmaf(wiv[m][1], ha.y, acc);
                acc = fmaf(wiv[m][2], ha.z, acc);
                acc = fmaf(wiv[m][3], ha.w, acc);
                acc = fmaf(whv[m][0], hb2.x, acc);
                acc = fmaf(whv[m][1], hb2.y, acc);
                acc = fmaf(whv[m][2], hb2.z, acc);
                acc = fmaf(whv[m][3], hb2.w, acc);
            }
            acc = fmaf(wit, ab[1024 + k0], acc);
            acc = fmaf(wht, bb[1024 + k0], acc);
#pragma unroll
            for (int off = 1; off < 32; off <<= 1) acc += __shfl_xor(acc, off);
            if (k0 == 0) gbuf[(t & 1) * 32 + row] = acc + bs;
            __syncthreads();                   // B
            if (w == 1 && lane == 0 && wg == 0 && (t & 255) == 255)
                st_u32(l1prog, (unsigned)(t + 1));        // backpressure progress
        }
        // final epilogue for t = TT-1
        if (w == 0 && lane < 8) {
            const float* gl = gbuf + ((TT - 1) & 1) * 32;
            const float gi = gl[lane], gf = gl[8 + lane];
            const float gg = gl[16 + lane], go = gl[24 + lane];
            const float iv = sigmf(gi), fv = sigmf(gf), gv = tanhf(gg), ov = sigmf(go);
            c_reg = fv * c_reg + iv * gv;
            float hv = ov * tanhf(c_reg);
            if (wg * 8 + lane >= HH) hv = 0.0f;
            h2hist[(size_t)(TT - 1) * HS + wg * 8 + lane] = hv;
        }
    }
}

// ---------- final projection: out[t] = lin_w . h2[t] + lin_b ----------
__global__ __launch_bounds__(256) void wn_proj(
    const float* __restrict__ h2,
    const float* __restrict__ lin_w,
    const float* __restrict__ lin_b,
    float* __restrict__ out)
{
    const int lane = threadIdx.x & 63;
    const int wv   = threadIdx.x >> 6;
    const int t    = blockIdx.x * 4 + wv;
    const float* hp = h2 + (size_t)t * HS;
    float acc = 0.0f;
#pragma unroll
    for (int m = 0; m < 4; ++m) {
        const int j = lane * 4 + m * 256;        // covers [0,1024)
        const float4 h4 = *(const float4*)(hp + j);
        const float4 w4 = *(const float4*)(lin_w + j);
        acc += h4.x * w4.x + h4.y * w4.y + h4.z * w4.z + h4.w * w4.w;
    }
    if (lane == 0) {
#pragma unroll
        for (int j = 1024; j < HH; ++j) acc += hp[j] * lin_w[j];
    }
#pragma unroll
    for (int off = 1; off < 64; off <<= 1) acc += __shfl_xor(acc, off);
    if (lane == 0) out[t] = acc + lin_b[0];
}

extern "C" void kernel_launch(void* const* d_in, const int* in_sizes, int n_in,
                              void* d_out, int out_size, void* d_ws, size_t ws_size,
                              hipStream_t stream) {
    const float* x     = (const float*)d_in[0];
    const float* w_ih0 = (const float*)d_in[1];
    const float* w_hh0 = (const float*)d_in[2];
    const float* b_ih0 = (const float*)d_in[3];
    const float* b_hh0 = (const float*)d_in[4];
    const float* w_ih1 = (const float*)d_in[5];
    const float* w_hh1 = (const float*)d_in[6];
    const float* b_ih1 = (const float*)d_in[7];
    const float* b_hh1 = (const float*)d_in[8];
    const float* lin_w = (const float*)d_in[9];
    const float* lin_b = (const float*)d_in[10];
    float* out = (float*)d_out;

    char* ws = (char*)d_ws;
    const size_t R0B = (size_t)R0 * HSU * 8;        //  8,650,752
    const size_t R1B = (size_t)16 * HSU * 8;        //    135,168
    const size_t H2B = (size_t)TT * HS * 4;         // 69,206,016
    u64* ring0 = (u64*)(ws);
    u64* ring1 = (u64*)(ws + R0B);
    float* h2hist = (float*)(ws + R0B + R1B);
    unsigned* l1prog = (unsigned*)(ws + R0B + R1B + H2B);
    // No init kernel: 0xAA poison never matches any tag (1..16384), and the
    // poisoned l1prog reads as negative -> L0 throttles until L1 publishes.

    wn_fused<<<NWGT, 1024, 0, stream>>>(x, w_ih0, w_hh0, b_ih0, b_hh0,
                                        w_ih1, w_hh1, b_ih1, b_hh1,
                                        ring0, ring1, h2hist, l1prog);
    wn_proj<<<TT / 4, 256, 0, stream>>>(h2hist, lin_w, lin_b, out);
}